// Round 6
// baseline (158.504 us; speedup 1.0000x reference)
//
#include <hip/hip_runtime.h>

// Problem constants (fixed by the reference).
#define T_LEN 4096
#define B_SZ  2
#define H_SZ  2048
#define NM    8            // N2 complex modes
#define BH    (B_SZ * H_SZ)
#define C_CH  64           // chunks (= wave size, for the shuffle scan)
#define LC    (T_LEN / C_CH)

// ---------------------------------------------------------------------------
// S4D via chunked linear recurrence (exact equivalent of the FFT conv):
//   S_n(t) = w_n * S_n(t-1) + x(t),  w_n = exp(dt*A_n)
//   out(t) = 2*Re( sum_n Cd_n * S_n(t) ) + D*x(t),  Cd = C*(w-1)/A
//
// states layout [c][b][n][h] float2: every k1/k3 access is a dense 512 B
// wave transaction. launch_bounds(256,4) = 128-VGPR cap (spill-free).
// Round-6: k2 rewritten as a wave-parallel Kogge-Stone scan (lane = chunk,
// uniform multiplier W = w^LC per (h,n), W^(2^k) via repeated squaring),
// with an LDS 64x64 tile transpose so global loads/stores stay h-coalesced.
// Round-5's serial k2 ran at 2 waves/CU with a 64-deep dependent walk.
// ---------------------------------------------------------------------------

template <int BT>
__global__ void __launch_bounds__(256, 4)
k1_chunk_end(const float* __restrict__ x,
             const float* __restrict__ log_dt,
             const float* __restrict__ Arl,
             const float* __restrict__ Aimp,
             float2* __restrict__ states) {
    int g = blockIdx.x * blockDim.x + threadIdx.x;   // [C_CH * BH)
    int h = g % H_SZ;
    int b = (g / H_SZ) % B_SZ;
    int c = g / BH;

    float dt = __expf(log_dt[h]);
    float wr[NM], wi[NM];
#pragma unroll
    for (int n = 0; n < NM; ++n) {
        float ar  = -__expf(Arl[h * NM + n]);
        float ai  = Aimp[h * NM + n];
        float er  = __expf(ar * dt);
        float ang = ai * dt;
        wr[n] = er * __cosf(ang);
        wi[n] = er * __sinf(ang);
    }

    float sr[NM], si[NM];
#pragma unroll
    for (int n = 0; n < NM; ++n) { sr[n] = 0.f; si[n] = 0.f; }

    const float* xp = x + (size_t)c * LC * BH + b * H_SZ + h;

    float buf[BT], nxt[BT];
#pragma unroll
    for (int i = 0; i < BT; ++i) buf[i] = xp[(size_t)i * BH];

#pragma unroll
    for (int tb = 0; tb < LC / BT; ++tb) {
        if (tb + 1 < LC / BT) {
#pragma unroll
            for (int i = 0; i < BT; ++i)
                nxt[i] = xp[(size_t)((tb + 1) * BT + i) * BH];
        }
#pragma unroll
        for (int i = 0; i < BT; ++i) {
            float xv = buf[i];
#pragma unroll
            for (int n = 0; n < NM; ++n) {
                float nsr = fmaf(wr[n], sr[n], fmaf(-wi[n], si[n], xv));
                float nsi = fmaf(wr[n], si[n], wi[n] * sr[n]);
                sr[n] = nsr; si[n] = nsi;
            }
        }
#pragma unroll
        for (int i = 0; i < BT; ++i) buf[i] = nxt[i];
    }

    // states[c][b][n][h]
    float2* st = states + (size_t)(c * B_SZ + b) * NM * H_SZ + h;
#pragma unroll
    for (int n = 0; n < NM; ++n) st[(size_t)n * H_SZ] = make_float2(sr[n], si[n]);
}

// Wave-parallel cross-chunk scan. One block handles a (b, n, 64-h) tile:
// load 64c x 64h coalesced -> LDS -> each wave scans 16 columns with lane=c
// Kogge-Stone shuffles -> exclusive shift -> LDS -> store back coalesced.
__global__ void __launch_bounds__(256, 4)
k2_carry_scan(const float* __restrict__ log_dt,
              const float* __restrict__ Arl,
              const float* __restrict__ Aimp,
              float2* __restrict__ states) {
    __shared__ float2 tile[C_CH][65];   // [c][hh], pad -> 2-way b64 conflicts (free)

    int blk = blockIdx.x;               // [B_SZ * NM * (H_SZ/64))
    int ht = blk % (H_SZ / 64);
    int n  = (blk / (H_SZ / 64)) % NM;
    int b  = blk / ((H_SZ / 64) * NM);
    int h0 = ht * 64;

    int tid  = threadIdx.x;
    int lane = tid & 63;
    int wv   = tid >> 6;                // 4 waves

    const size_t cstride = (size_t)B_SZ * NM * H_SZ;          // chunk-to-chunk
    float2* base = states + ((size_t)b * NM + n) * H_SZ + h0;  // + c*cstride + hh

    // ---- load (h-coalesced) ----
#pragma unroll
    for (int i = 0; i < C_CH / 4; ++i) {
        int c = i * 4 + wv;
        tile[c][lane] = base[(size_t)c * cstride + lane];
    }
    __syncthreads();

    // ---- scan 16 columns per wave, lane = chunk index ----
#pragma unroll
    for (int ci = 0; ci < 16; ++ci) {
        int hh = wv * 16 + ci;
        int h  = h0 + hh;
        // W = w^LC = exp(dt*A*LC), uniform across lanes for this column
        float dt  = __expf(log_dt[h]);
        float ar  = -__expf(Arl[h * NM + n]);
        float ai  = Aimp[h * NM + n];
        float er  = __expf(ar * dt * (float)LC);
        float ang = ai * dt * (float)LC;
        float Wr = er * __cosf(ang), Wi = er * __sinf(ang);

        float2 v = tile[lane][hh];
        float br = v.x, bi = v.y;

        float Wkr = Wr, Wki = Wi;
#pragma unroll
        for (int k = 1; k < C_CH; k <<= 1) {
            float pr = __shfl_up(br, k);
            float pi = __shfl_up(bi, k);
            if (lane >= k) {
                br = fmaf(Wkr, pr, fmaf(-Wki, pi, br));
                bi = fmaf(Wkr, pi, fmaf(Wki, pr, bi));
            }
            float nWr = Wkr * Wkr - Wki * Wki;
            float nWi = 2.f * Wkr * Wki;
            Wkr = nWr; Wki = nWi;
        }
        // exclusive: carry INTO chunk c = inclusive prefix of chunks < c
        float er2 = __shfl_up(br, 1);
        float ei2 = __shfl_up(bi, 1);
        if (lane == 0) { er2 = 0.f; ei2 = 0.f; }
        tile[lane][hh] = make_float2(er2, ei2);
    }
    __syncthreads();

    // ---- store back (h-coalesced) ----
#pragma unroll
    for (int i = 0; i < C_CH / 4; ++i) {
        int c = i * 4 + wv;
        base[(size_t)c * cstride + lane] = tile[c][lane];
    }
}

template <int BT>
__global__ void __launch_bounds__(256, 4)
k3_output(const float* __restrict__ x,
          const float* __restrict__ Dp,
          const float* __restrict__ log_dt,
          const float* __restrict__ Arl,
          const float* __restrict__ Aimp,
          const float* __restrict__ Crep,
          const float* __restrict__ Cimp,
          const float2* __restrict__ states,
          float* __restrict__ out) {
    int g = blockIdx.x * blockDim.x + threadIdx.x;   // [C_CH * BH)
    int h = g % H_SZ;
    int b = (g / H_SZ) % B_SZ;
    int c = g / BH;

    float dt = __expf(log_dt[h]);
    float wr[NM], wi[NM], cdr[NM], cdi[NM];
#pragma unroll
    for (int n = 0; n < NM; ++n) {
        float ar  = -__expf(Arl[h * NM + n]);
        float ai  = Aimp[h * NM + n];
        float er  = __expf(ar * dt);
        float ang = ai * dt;
        float wrn = er * __cosf(ang);
        float win = er * __sinf(ang);
        wr[n] = wrn; wi[n] = win;
        // Cd = (Cre + i*Cim) * (w - 1) / A  (divide via conj(A)/|A|^2)
        float inv = 1.0f / (ar * ar + ai * ai);
        float tr = ((wrn - 1.f) * ar + win * ai) * inv;
        float ti = (win * ar - (wrn - 1.f) * ai) * inv;
        float Cre = Crep[h * NM + n], Cim = Cimp[h * NM + n];
        cdr[n] = Cre * tr - Cim * ti;
        cdi[n] = Cre * ti + Cim * tr;
    }

    // carry-in: states[c][b][n][h]
    const float2* st = states + (size_t)(c * B_SZ + b) * NM * H_SZ + h;
    float sr[NM], si[NM];
#pragma unroll
    for (int n = 0; n < NM; ++n) {
        float2 v = st[(size_t)n * H_SZ];
        sr[n] = v.x; si[n] = v.y;
    }

    float Dv = Dp[h];
    const float* xp = x + (size_t)c * LC * BH + b * H_SZ + h;
    float* op = out + (size_t)c * LC * BH + b * H_SZ + h;

    float buf[BT], nxt[BT];
#pragma unroll
    for (int i = 0; i < BT; ++i) buf[i] = xp[(size_t)i * BH];

#pragma unroll
    for (int tb = 0; tb < LC / BT; ++tb) {
        if (tb + 1 < LC / BT) {
#pragma unroll
            for (int i = 0; i < BT; ++i)
                nxt[i] = xp[(size_t)((tb + 1) * BT + i) * BH];
        }
#pragma unroll
        for (int i = 0; i < BT; ++i) {
            float xv = buf[i];
            float y = 0.f;
#pragma unroll
            for (int n = 0; n < NM; ++n) {
                float nsr = fmaf(wr[n], sr[n], fmaf(-wi[n], si[n], xv));
                float nsi = fmaf(wr[n], si[n], wi[n] * sr[n]);
                sr[n] = nsr; si[n] = nsi;
                y = fmaf(cdr[n], nsr, y);
                y = fmaf(-cdi[n], nsi, y);
            }
            float ov = fmaf(Dv, xv, 2.0f * y);
            __builtin_nontemporal_store(ov, op + (size_t)(tb * BT + i) * BH);
        }
#pragma unroll
        for (int i = 0; i < BT; ++i) buf[i] = nxt[i];
    }
}

extern "C" void kernel_launch(void* const* d_in, const int* in_sizes, int n_in,
                              void* d_out, int out_size, void* d_ws, size_t ws_size,
                              hipStream_t stream) {
    const float* x      = (const float*)d_in[0];
    const float* Dp     = (const float*)d_in[1];
    const float* log_dt = (const float*)d_in[2];
    const float* Arl    = (const float*)d_in[3];
    const float* Aimp   = (const float*)d_in[4];
    const float* Cre    = (const float*)d_in[5];
    const float* Cim    = (const float*)d_in[6];
    float* out = (float*)d_out;
    float2* states = (float2*)d_ws;   // C_CH*BH*NM float2 = 16.8 MB

    int total1 = C_CH * BH;                          // 262144 threads
    k1_chunk_end<16><<<total1 / 256, 256, 0, stream>>>(x, log_dt, Arl, Aimp, states);

    int blocks2 = B_SZ * NM * (H_SZ / 64);           // 512 blocks
    k2_carry_scan<<<blocks2, 256, 0, stream>>>(log_dt, Arl, Aimp, states);

    k3_output<8><<<total1 / 256, 256, 0, stream>>>(x, Dp, log_dt, Arl, Aimp,
                                                   Cre, Cim, states, out);
}